// Round 1
// baseline (26286.014 us; speedup 1.0000x reference)
//
#include <hip/hip_runtime.h>

#define N_NODES 20000
#define N_EDGES 320000
#define HDIM 128

// One thread per (edge, out_col): m = relu([x_src, ea] @ We + be); atomicAdd into A[dst].
__global__ void edge_kernel(const float* __restrict__ x, int xstride, int xoff, int D,
                            const int* __restrict__ ei, const float* __restrict__ ea,
                            const float* __restrict__ We, const float* __restrict__ be,
                            float* __restrict__ A, int Hout)
{
    long long tid = (long long)blockIdx.x * blockDim.x + threadIdx.x;
    long long total = (long long)N_EDGES * Hout;
    if (tid >= total) return;
    int e = (int)(tid / Hout);
    int j = (int)(tid % Hout);
    int src = ei[e];
    int dst = ei[N_EDGES + e];
    float acc = be[j];
    const float* xr = x + (long long)src * xstride + xoff;
    for (int k = 0; k < D; ++k)
        acc = fmaf(xr[k], We[k * Hout + j], acc);
    const float* er = ea + (long long)e * 4;
    for (int k = 0; k < 4; ++k)
        acc = fmaf(er[k], We[(D + k) * Hout + j], acc);
    acc = fmaxf(acc, 0.0f);
    atomicAdd(&A[(long long)dst * Hout + j], acc);
}

// One thread per (node, out_col): h = relu([x, aggr] @ Wn + bn).
__global__ void node_kernel(const float* __restrict__ x, int xstride, int xoff, int D,
                            const float* __restrict__ A, int HA,
                            const float* __restrict__ Wn, const float* __restrict__ bn,
                            float* __restrict__ out, int ostride, int ooff, int Hout)
{
    int tid = blockIdx.x * blockDim.x + threadIdx.x;
    int total = N_NODES * Hout;
    if (tid >= total) return;
    int n = tid / Hout;
    int j = tid % Hout;
    float acc = bn[j];
    const float* xr = x + (long long)n * xstride + xoff;
    for (int k = 0; k < D; ++k)
        acc = fmaf(xr[k], Wn[k * Hout + j], acc);
    const float* ar = A + (long long)n * HA;
    for (int k = 0; k < HA; ++k)
        acc = fmaf(ar[k], Wn[(D + k) * Hout + j], acc);
    out[(long long)n * ostride + ooff + j] = fmaxf(acc, 0.0f);
}

extern "C" void kernel_launch(void* const* d_in, const int* in_sizes, int n_in,
                              void* d_out, int out_size, void* d_ws, size_t ws_size,
                              hipStream_t stream) {
    const float* x    = (const float*)d_in[0];
    const int*   ei   = (const int*)d_in[1];
    const float* ea   = (const float*)d_in[2];
    const float* We1  = (const float*)d_in[3];
    const float* be1  = (const float*)d_in[4];
    const float* Wn1  = (const float*)d_in[5];
    const float* bn1  = (const float*)d_in[6];
    const float* WeM  = (const float*)d_in[7];
    const float* beM  = (const float*)d_in[8];
    const float* WnM  = (const float*)d_in[9];
    const float* bnM  = (const float*)d_in[10];
    const float* WeC  = (const float*)d_in[11];
    const float* beC  = (const float*)d_in[12];
    const float* WnC  = (const float*)d_in[13];
    const float* bnC  = (const float*)d_in[14];
    const float* WeL  = (const float*)d_in[15];
    const float* beL  = (const float*)d_in[16];
    const float* WnL  = (const float*)d_in[17];
    const float* bnL  = (const float*)d_in[18];

    float* A  = (float*)d_ws;                               // [N, 128]
    float* XS = A + (size_t)N_NODES * HDIM;                 // [N, 896] = h1..h7
    float* HC = XS + (size_t)N_NODES * 7 * HDIM;            // [N, 128]
    float* out = (float*)d_out;                             // [N, 8]

    auto edge_layer = [&](const float* xin, int xs, int xo, int D,
                          const float* We, const float* be, int Hout) {
        hipMemsetAsync(A, 0, (size_t)N_NODES * Hout * sizeof(float), stream);
        long long total = (long long)N_EDGES * Hout;
        int blocks = (int)((total + 255) / 256);
        edge_kernel<<<blocks, 256, 0, stream>>>(xin, xs, xo, D, ei, ea, We, be, A, Hout);
    };
    auto node_layer = [&](const float* xin, int xs, int xo, int D, int HA,
                          const float* Wn, const float* bn,
                          float* o, int os, int oo, int Hout) {
        int total = N_NODES * Hout;
        int blocks = (total + 255) / 256;
        node_kernel<<<blocks, 256, 0, stream>>>(xin, xs, xo, D, A, HA, Wn, bn, o, os, oo, Hout);
    };

    // layer 1: node_in = 8
    edge_layer(x, 8, 0, 8, We1, be1, HDIM);
    node_layer(x, 8, 0, 8, HDIM, Wn1, bn1, XS, 7 * HDIM, 0, HDIM);

    // layers 2..7: node_in = 128
    for (int i = 0; i < 6; ++i) {
        edge_layer(XS, 7 * HDIM, i * HDIM, HDIM, WeM + (size_t)i * 132 * HDIM, beM + i * HDIM, HDIM);
        node_layer(XS, 7 * HDIM, i * HDIM, HDIM, HDIM, WnM + (size_t)i * 256 * HDIM, bnM + i * HDIM,
                   XS, 7 * HDIM, (i + 1) * HDIM, HDIM);
    }

    // concat layer: node_in = 896
    edge_layer(XS, 7 * HDIM, 0, 7 * HDIM, WeC, beC, HDIM);
    node_layer(XS, 7 * HDIM, 0, 7 * HDIM, HDIM, WnC, bnC, HC, HDIM, 0, HDIM);

    // last layer: node_in = 128, out = 8
    edge_layer(HC, HDIM, 0, HDIM, WeL, beL, 8);
    node_layer(HC, HDIM, 0, HDIM, 8, WnL, bnL, out, 8, 0, 8);
}

// Round 2
// 3102.832 us; speedup vs baseline: 8.4716x; 8.4716x over previous
//
#include <hip/hip_runtime.h>

#define NN 20000
#define NE 320000
#define HD 128
#define BM 128
#define BN 128
#define BK 32

// Generic fused layer GEMM: rows are [seg1 (D floats, via optional src gather) | seg2].
// Out = relu(row @ W + bias), either scattered (atomicAdd into Out[dst[row]]) or stored.
template<bool SCATTER>
__global__ __launch_bounds__(256, 4)
void gemm_layer(const float* __restrict__ base1, int s1, int xoff, int D,
                const float* __restrict__ base2, int s2,
                const int* __restrict__ srcidx,   // nullptr -> identity
                const int* __restrict__ dstidx,   // used when SCATTER
                const float* __restrict__ W, const float* __restrict__ bias,
                float* __restrict__ Out, long long ostride, int ooff,
                int M, int Ktot)
{
    __shared__ float As[BM][BK + 1];
    __shared__ float Bs[BK * BN];

    const int t  = threadIdx.x;
    const int tx = t & 15;
    const int ty = t >> 4;

    // staging assignment: 2 threads per row, 16 k-values each
    const int srow  = t >> 1;
    const int kbase = (t & 1) * 16;
    int gr  = blockIdx.x * BM + srow;
    int grc = gr < M ? gr : M - 1;
    int r1  = srcidx ? srcidx[grc] : grc;
    const float* p1 = base1 + (long long)r1 * s1 + xoff;
    const float* p2 = base2 + (long long)grc * s2;

    float acc[8][8];
    #pragma unroll
    for (int i = 0; i < 8; ++i)
        #pragma unroll
        for (int u = 0; u < 8; ++u) acc[i][u] = 0.f;

    const int ntiles = (Ktot + BK - 1) / BK;
    for (int kt = 0; kt < ntiles; ++kt) {
        // ---- stage A tile (gathered rows, zero-padded past Ktot)
        int gk0 = kt * BK + kbase;
        if (gk0 + 15 < D) {
            #pragma unroll
            for (int p = 0; p < 4; ++p) {
                float4 v = *reinterpret_cast<const float4*>(p1 + gk0 + p * 4);
                As[srow][kbase + p * 4 + 0] = v.x;
                As[srow][kbase + p * 4 + 1] = v.y;
                As[srow][kbase + p * 4 + 2] = v.z;
                As[srow][kbase + p * 4 + 3] = v.w;
            }
        } else {
            #pragma unroll
            for (int i = 0; i < 16; ++i) {
                int gk = gk0 + i;
                float v = 0.f;
                if (gk < D) v = p1[gk];
                else if (gk < Ktot) v = p2[gk - D];
                As[srow][kbase + i] = v;
            }
        }
        // ---- stage B tile (coalesced float4, zero-padded)
        #pragma unroll
        for (int p = 0; p < 4; ++p) {
            int idx = (p * 256 + t) * 4;
            int kk  = idx >> 7;
            int nn  = idx & 127;
            int gk  = kt * BK + kk;
            float4 v = {0.f, 0.f, 0.f, 0.f};
            if (gk < Ktot) v = *reinterpret_cast<const float4*>(W + (long long)gk * BN + nn);
            *reinterpret_cast<float4*>(&Bs[kk * BN + nn]) = v;
        }
        __syncthreads();
        // ---- compute: 8x8 per thread, rows ty*8+i, cols tx+16u
        #pragma unroll 8
        for (int kk = 0; kk < BK; ++kk) {
            float a[8], b[8];
            #pragma unroll
            for (int i = 0; i < 8; ++i) a[i] = As[ty * 8 + i][kk];
            #pragma unroll
            for (int u = 0; u < 8; ++u) b[u] = Bs[kk * BN + tx + 16 * u];
            #pragma unroll
            for (int i = 0; i < 8; ++i)
                #pragma unroll
                for (int u = 0; u < 8; ++u)
                    acc[i][u] = fmaf(a[i], b[u], acc[i][u]);
        }
        __syncthreads();
    }

    float bv[8];
    #pragma unroll
    for (int u = 0; u < 8; ++u) bv[u] = bias[tx + 16 * u];

    #pragma unroll
    for (int i = 0; i < 8; ++i) {
        int orow = blockIdx.x * BM + ty * 8 + i;
        if (orow < M) {
            long long dr = SCATTER ? (long long)dstidx[orow] : (long long)orow;
            float* op = Out + dr * ostride + ooff;
            #pragma unroll
            for (int u = 0; u < 8; ++u) {
                float v = fmaxf(acc[i][u] + bv[u], 0.f);
                if (SCATTER) atomicAdd(&op[tx + 16 * u], v);
                else         op[tx + 16 * u] = v;
            }
        }
    }
}

// Last edge layer: Hout=8, D=128 (+4 edge attrs). Thread per edge, weights in LDS.
__global__ void edge_small(const float* __restrict__ x,
                           const int* __restrict__ ei, const float* __restrict__ ea,
                           const float* __restrict__ We, const float* __restrict__ be,
                           float* __restrict__ A)
{
    __shared__ float sW[132 * 8];
    for (int idx = threadIdx.x; idx < 132 * 8; idx += 256) sW[idx] = We[idx];
    __syncthreads();
    int e = blockIdx.x * 256 + threadIdx.x;
    if (e >= NE) return;
    int src = ei[e], dst = ei[NE + e];
    float acc[8];
    #pragma unroll
    for (int j = 0; j < 8; ++j) acc[j] = be[j];
    const float* xr = x + (long long)src * HD;
    for (int k4 = 0; k4 < HD / 4; ++k4) {
        float4 v = *reinterpret_cast<const float4*>(xr + k4 * 4);
        float vv[4] = {v.x, v.y, v.z, v.w};
        #pragma unroll
        for (int c = 0; c < 4; ++c)
            #pragma unroll
            for (int j = 0; j < 8; ++j)
                acc[j] = fmaf(vv[c], sW[(k4 * 4 + c) * 8 + j], acc[j]);
    }
    #pragma unroll
    for (int c = 0; c < 4; ++c) {
        float v = ea[(long long)e * 4 + c];
        #pragma unroll
        for (int j = 0; j < 8; ++j)
            acc[j] = fmaf(v, sW[(HD + c) * 8 + j], acc[j]);
    }
    #pragma unroll
    for (int j = 0; j < 8; ++j)
        atomicAdd(&A[(long long)dst * 8 + j], fmaxf(acc[j], 0.f));
}

// Last node layer: Hout=8, K=136. Thread per node.
__global__ void node_small(const float* __restrict__ x, const float* __restrict__ Agg,
                           const float* __restrict__ Wn, const float* __restrict__ bn,
                           float* __restrict__ out)
{
    __shared__ float sW[136 * 8];
    for (int idx = threadIdx.x; idx < 136 * 8; idx += 256) sW[idx] = Wn[idx];
    __syncthreads();
    int n = blockIdx.x * 256 + threadIdx.x;
    if (n >= NN) return;
    float acc[8];
    #pragma unroll
    for (int j = 0; j < 8; ++j) acc[j] = bn[j];
    const float* xr = x + (long long)n * HD;
    for (int k4 = 0; k4 < HD / 4; ++k4) {
        float4 v = *reinterpret_cast<const float4*>(xr + k4 * 4);
        float vv[4] = {v.x, v.y, v.z, v.w};
        #pragma unroll
        for (int c = 0; c < 4; ++c)
            #pragma unroll
            for (int j = 0; j < 8; ++j)
                acc[j] = fmaf(vv[c], sW[(k4 * 4 + c) * 8 + j], acc[j]);
    }
    const float* ar = Agg + (long long)n * 8;
    #pragma unroll
    for (int c = 0; c < 8; ++c) {
        float v = ar[c];
        #pragma unroll
        for (int j = 0; j < 8; ++j)
            acc[j] = fmaf(v, sW[(HD + c) * 8 + j], acc[j]);
    }
    #pragma unroll
    for (int j = 0; j < 8; ++j)
        out[(long long)n * 8 + j] = fmaxf(acc[j], 0.f);
}

extern "C" void kernel_launch(void* const* d_in, const int* in_sizes, int n_in,
                              void* d_out, int out_size, void* d_ws, size_t ws_size,
                              hipStream_t stream) {
    const float* x    = (const float*)d_in[0];
    const int*   ei   = (const int*)d_in[1];
    const float* ea   = (const float*)d_in[2];
    const float* We1  = (const float*)d_in[3];
    const float* be1  = (const float*)d_in[4];
    const float* Wn1  = (const float*)d_in[5];
    const float* bn1  = (const float*)d_in[6];
    const float* WeM  = (const float*)d_in[7];
    const float* beM  = (const float*)d_in[8];
    const float* WnM  = (const float*)d_in[9];
    const float* bnM  = (const float*)d_in[10];
    const float* WeC  = (const float*)d_in[11];
    const float* beC  = (const float*)d_in[12];
    const float* WnC  = (const float*)d_in[13];
    const float* bnC  = (const float*)d_in[14];
    const float* WeL  = (const float*)d_in[15];
    const float* beL  = (const float*)d_in[16];
    const float* WnL  = (const float*)d_in[17];
    const float* bnL  = (const float*)d_in[18];

    float* Agg = (float*)d_ws;                         // [N, 128] (also reused as [N,8])
    float* XS  = Agg + (size_t)NN * HD;                // [N, 896] = h1..h7
    float* HC  = XS + (size_t)NN * 7 * HD;             // [N, 128]
    float* out = (float*)d_out;                        // [N, 8]

    const int*  src = ei;
    const int*  dst = ei + NE;
    const int   egrid = NE / BM;                       // 2500
    const int   ngrid = (NN + BM - 1) / BM;            // 157

    auto edge_gemm = [&](const float* b1, int s1, int xoff, int D,
                         const float* W, const float* be, int Ktot) {
        hipMemsetAsync(Agg, 0, (size_t)NN * HD * sizeof(float), stream);
        gemm_layer<true><<<egrid, 256, 0, stream>>>(b1, s1, xoff, D, ea, 4, src, dst,
                                                    W, be, Agg, HD, 0, NE, Ktot);
    };
    auto node_gemm = [&](const float* b1, int s1, int xoff, int D, int HA,
                         const float* W, const float* bn,
                         float* o, long long os, int oo, int Ktot) {
        gemm_layer<false><<<ngrid, 256, 0, stream>>>(b1, s1, xoff, D, Agg, HA,
                                                     nullptr, nullptr,
                                                     W, bn, o, os, oo, NN, Ktot);
    };

    // layer 1: node_in = 8
    edge_gemm(x, 8, 0, 8, We1, be1, 12);
    node_gemm(x, 8, 0, 8, HD, Wn1, bn1, XS, 7 * HD, 0, 136);

    // layers 2..7: node_in = 128
    for (int i = 0; i < 6; ++i) {
        edge_gemm(XS, 7 * HD, i * HD, HD, WeM + (size_t)i * 132 * HD, beM + i * HD, 132);
        node_gemm(XS, 7 * HD, i * HD, HD, HD, WnM + (size_t)i * 256 * HD, bnM + i * HD,
                  XS, 7 * HD, (i + 1) * HD, 256);
    }

    // concat layer: node_in = 896
    edge_gemm(XS, 7 * HD, 0, 7 * HD, WeC, beC, 900);
    node_gemm(XS, 7 * HD, 0, 7 * HD, HD, WnC, bnC, HC, HD, 0, 1024);

    // last layer: node_in = 128, out = 8
    hipMemsetAsync(Agg, 0, (size_t)NN * 8 * sizeof(float), stream);
    edge_small<<<NE / 256, 256, 0, stream>>>(HC, ei, ea, WeL, beL, Agg);
    node_small<<<(NN + 255) / 256, 256, 0, stream>>>(HC, Agg, WnL, bnL, out);
}

// Round 3
// 1570.595 us; speedup vs baseline: 16.7363x; 1.9756x over previous
//
#include <hip/hip_runtime.h>

#define NN 20000
#define NE 320000
#define HD 128

typedef short     s16x8 __attribute__((ext_vector_type(8)));
typedef unsigned short u16x8 __attribute__((ext_vector_type(8)));
typedef float     f32x4 __attribute__((ext_vector_type(4)));

__device__ __forceinline__ float b2f(unsigned short u) {
    union { unsigned int i; float f; } c; c.i = ((unsigned int)u) << 16; return c.f;
}
__device__ __forceinline__ unsigned short f2b(float f) {
    union { float f; unsigned int i; } c; c.f = f;
    unsigned int x = c.i + 0x7FFFu + ((c.i >> 16) & 1u);
    return (unsigned short)(x >> 16);
}

__global__ void cvt_bf16(const float* __restrict__ in, unsigned short* __restrict__ out, int n) {
    int i = blockIdx.x * 256 + threadIdx.x;
    if (i < n) out[i] = f2b(in[i]);
}

// WT[n*K + k] = bf16(W[k*128 + n]) — weight transpose+convert (only first K rows of W used)
__global__ void cvt_transpose(const float* __restrict__ W, unsigned short* __restrict__ WT, int K) {
    int tid = blockIdx.x * 256 + threadIdx.x;
    if (tid >= K * HD) return;
    int n = tid & (HD - 1), k = tid >> 7;
    WT[(size_t)n * K + k] = f2b(W[(size_t)k * HD + n]);
}

// ---------------- MFMA layer: C = relu(A @ W + bias [+ ea @ Wea]), N=128 fixed.
// A row = [seg1 (bf16, D1 elems, optional gather) | seg2 (fp32, D2 elems)], K = D1+D2 mult of 32.
// SCATTER: atomicAdd into OutF[dst[row]*128 + col]; else store bf16 OutB[row*ostride + ooff + col].
template<bool SCATTER>
__global__ __launch_bounds__(256)
void mfma_layer(const unsigned short* __restrict__ seg1, long long s1, int xoff, int D1,
                const float* __restrict__ seg2, long long s2,
                const int* __restrict__ srcidx, const int* __restrict__ dstidx,
                const unsigned short* __restrict__ WT,   // [128][K] bf16
                const float* __restrict__ bias,
                const float* __restrict__ Wea,           // [4][128] fp32 (SCATTER only)
                const float* __restrict__ ea,            // [E][4]     (SCATTER only)
                float* __restrict__ OutF,
                unsigned short* __restrict__ OutB, long long ostride, int ooff,
                int M, int K)
{
    __shared__ unsigned short As[128 * 32];
    __shared__ unsigned short Bs[128 * 32];
    __shared__ float eas[128 * 4];

    const int t    = threadIdx.x;
    const int lane = t & 63;
    const int wid  = t >> 6;
    const int wm   = wid >> 1, wn = wid & 1;
    const int ln   = lane & 15, kb = lane >> 4;
    const int bRow = blockIdx.x * 128;

    // staging: 2 threads per row, 16 bf16 (32B) each
    const int srow = t >> 1, half = t & 1;
    int gr  = bRow + srow;
    int grc = gr < M ? gr : M - 1;
    long long r1 = srcidx ? (long long)srcidx[grc] : (long long)grc;
    const unsigned short* p1 = seg1 + r1 * s1 + xoff;
    const float* p2 = seg2 ? seg2 + (long long)grc * s2 : nullptr;
    const unsigned short* pb = WT + (long long)srow * K;
    const int sl0 = ((half << 1)    ) ^ (srow & 3);
    const int sl1 = ((half << 1) + 1) ^ (srow & 3);

    if (SCATTER && t < 128) {
        int er = bRow + t;
        if (er < M) *(float4*)&eas[t * 4] = *(const float4*)(ea + (long long)er * 4);
    }

    f32x4 acc[4][4];
    #pragma unroll
    for (int m = 0; m < 4; ++m)
        #pragma unroll
        for (int n = 0; n < 4; ++n) acc[m][n] = f32x4{0.f, 0.f, 0.f, 0.f};

    const int nkt = K >> 5;
    for (int kt = 0; kt < nkt; ++kt) {
        int k0 = (kt << 5) + half * 16;
        u16x8 c0, c1;
        if (k0 + 16 <= D1) {
            const u16x8* sp = (const u16x8*)(p1 + k0);
            c0 = sp[0]; c1 = sp[1];
        } else {
            const float* fp = p2 + (k0 - D1);
            #pragma unroll
            for (int j = 0; j < 8; ++j) { c0[j] = f2b(fp[j]); c1[j] = f2b(fp[8 + j]); }
        }
        *(u16x8*)&As[srow * 32 + sl0 * 8] = c0;
        *(u16x8*)&As[srow * 32 + sl1 * 8] = c1;
        {
            const u16x8* sp = (const u16x8*)(pb + (kt << 5) + half * 16);
            u16x8 b0 = sp[0], b1 = sp[1];
            *(u16x8*)&Bs[srow * 32 + sl0 * 8] = b0;
            *(u16x8*)&Bs[srow * 32 + sl1 * 8] = b1;
        }
        __syncthreads();

        s16x8 af[4], bfr[4];
        #pragma unroll
        for (int m = 0; m < 4; ++m) {
            int row = wm * 64 + m * 16 + ln;
            af[m] = *(const s16x8*)&As[row * 32 + ((kb ^ (row & 3)) << 3)];
        }
        #pragma unroll
        for (int n = 0; n < 4; ++n) {
            int row = wn * 64 + n * 16 + ln;
            bfr[n] = *(const s16x8*)&Bs[row * 32 + ((kb ^ (row & 3)) << 3)];
        }
        #pragma unroll
        for (int m = 0; m < 4; ++m)
            #pragma unroll
            for (int n = 0; n < 4; ++n)
                acc[m][n] = __builtin_amdgcn_mfma_f32_16x16x32_bf16(af[m], bfr[n], acc[m][n], 0, 0, 0);
        __syncthreads();
    }

    float bv[4];
    #pragma unroll
    for (int n = 0; n < 4; ++n) bv[n] = bias[wn * 64 + n * 16 + ln];

    if (SCATTER) {
        float we[4][4];
        #pragma unroll
        for (int c = 0; c < 4; ++c)
            #pragma unroll
            for (int n = 0; n < 4; ++n) we[c][n] = Wea[c * HD + wn * 64 + n * 16 + ln];
        #pragma unroll
        for (int m = 0; m < 4; ++m) {
            #pragma unroll
            for (int r = 0; r < 4; ++r) {
                int lrow = wm * 64 + m * 16 + kb * 4 + r;
                int grow = bRow + lrow;
                if (grow < M) {
                    float4 e4 = *(const float4*)&eas[lrow * 4];
                    long long drow = dstidx[grow];
                    float* op = OutF + drow * HD;
                    #pragma unroll
                    for (int n = 0; n < 4; ++n) {
                        float v = acc[m][n][r] + bv[n]
                                + e4.x * we[0][n] + e4.y * we[1][n]
                                + e4.z * we[2][n] + e4.w * we[3][n];
                        atomicAdd(op + wn * 64 + n * 16 + ln, fmaxf(v, 0.f));
                    }
                }
            }
        }
    } else {
        #pragma unroll
        for (int m = 0; m < 4; ++m) {
            #pragma unroll
            for (int r = 0; r < 4; ++r) {
                int grow = bRow + wm * 64 + m * 16 + kb * 4 + r;
                if (grow < M) {
                    unsigned short* op = OutB + (long long)grow * ostride + ooff;
                    #pragma unroll
                    for (int n = 0; n < 4; ++n)
                        op[wn * 64 + n * 16 + ln] = f2b(fmaxf(acc[m][n][r] + bv[n], 0.f));
                }
            }
        }
    }
}

// ---------------- fp32 fallback GEMM for layer 1 (tiny K). seg1 is bf16 now.
template<bool SCATTER, bool OBF16>
__global__ __launch_bounds__(256, 4)
void gemm_layer(const unsigned short* __restrict__ base1, int s1, int D,
                const float* __restrict__ base2, int s2,
                const int* __restrict__ srcidx, const int* __restrict__ dstidx,
                const float* __restrict__ W, const float* __restrict__ bias,
                float* __restrict__ OutF, unsigned short* __restrict__ OutB,
                long long ostride, int M, int Ktot)
{
    __shared__ float As[128][33];
    __shared__ float Bs[32 * 128];

    const int t  = threadIdx.x;
    const int tx = t & 15;
    const int ty = t >> 4;
    const int srow  = t >> 1;
    const int kbase = (t & 1) * 16;
    int gr  = blockIdx.x * 128 + srow;
    int grc = gr < M ? gr : M - 1;
    long long r1 = srcidx ? (long long)srcidx[grc] : (long long)grc;
    const unsigned short* p1 = base1 + r1 * s1;
    const float* p2 = base2 + (long long)grc * s2;

    float acc[8][8];
    #pragma unroll
    for (int i = 0; i < 8; ++i)
        #pragma unroll
        for (int u = 0; u < 8; ++u) acc[i][u] = 0.f;

    const int ntiles = (Ktot + 31) / 32;
    for (int kt = 0; kt < ntiles; ++kt) {
        #pragma unroll
        for (int i = 0; i < 16; ++i) {
            int gk = kt * 32 + kbase + i;
            float v = 0.f;
            if (gk < D) v = b2f(p1[gk]);
            else if (gk < Ktot) v = p2[gk - D];
            As[srow][kbase + i] = v;
        }
        #pragma unroll
        for (int p = 0; p < 4; ++p) {
            int idx = (p * 256 + t) * 4;
            int kk  = idx >> 7;
            int nn  = idx & 127;
            int gk  = kt * 32 + kk;
            float4 v = {0.f, 0.f, 0.f, 0.f};
            if (gk < Ktot) v = *reinterpret_cast<const float4*>(W + (long long)gk * 128 + nn);
            *reinterpret_cast<float4*>(&Bs[kk * 128 + nn]) = v;
        }
        __syncthreads();
        #pragma unroll 8
        for (int kk = 0; kk < 32; ++kk) {
            float a[8], b[8];
            #pragma unroll
            for (int i = 0; i < 8; ++i) a[i] = As[ty * 8 + i][kk];
            #pragma unroll
            for (int u = 0; u < 8; ++u) b[u] = Bs[kk * 128 + tx + 16 * u];
            #pragma unroll
            for (int i = 0; i < 8; ++i)
                #pragma unroll
                for (int u = 0; u < 8; ++u)
                    acc[i][u] = fmaf(a[i], b[u], acc[i][u]);
        }
        __syncthreads();
    }

    float bv[8];
    #pragma unroll
    for (int u = 0; u < 8; ++u) bv[u] = bias[tx + 16 * u];

    #pragma unroll
    for (int i = 0; i < 8; ++i) {
        int orow = blockIdx.x * 128 + ty * 8 + i;
        if (orow < M) {
            #pragma unroll
            for (int u = 0; u < 8; ++u) {
                float v = fmaxf(acc[i][u] + bv[u], 0.f);
                if (SCATTER) {
                    long long dr = dstidx[orow];
                    atomicAdd(OutF + dr * 128 + tx + 16 * u, v);
                } else if (OBF16) {
                    OutB[(long long)orow * ostride + tx + 16 * u] = f2b(v);
                } else {
                    OutF[(long long)orow * ostride + tx + 16 * u] = v;
                }
            }
        }
    }
}

// ---------------- last layer (Hout=8) small kernels, bf16 node input
__global__ void edge_small(const unsigned short* __restrict__ x,
                           const int* __restrict__ ei, const float* __restrict__ ea,
                           const float* __restrict__ We, const float* __restrict__ be,
                           float* __restrict__ A)
{
    __shared__ float sW[132 * 8];
    for (int idx = threadIdx.x; idx < 132 * 8; idx += 256) sW[idx] = We[idx];
    __syncthreads();
    int e = blockIdx.x * 256 + threadIdx.x;
    if (e >= NE) return;
    int src = ei[e], dst = ei[NE + e];
    float acc[8];
    #pragma unroll
    for (int j = 0; j < 8; ++j) acc[j] = be[j];
    const unsigned short* xr = x + (long long)src * HD;
    for (int k8 = 0; k8 < HD / 8; ++k8) {
        u16x8 v = *(const u16x8*)(xr + k8 * 8);
        #pragma unroll
        for (int c = 0; c < 8; ++c) {
            float f = b2f(v[c]);
            #pragma unroll
            for (int j = 0; j < 8; ++j)
                acc[j] = fmaf(f, sW[(k8 * 8 + c) * 8 + j], acc[j]);
        }
    }
    #pragma unroll
    for (int c = 0; c < 4; ++c) {
        float v = ea[(long long)e * 4 + c];
        #pragma unroll
        for (int j = 0; j < 8; ++j)
            acc[j] = fmaf(v, sW[(HD + c) * 8 + j], acc[j]);
    }
    #pragma unroll
    for (int j = 0; j < 8; ++j)
        atomicAdd(&A[(long long)dst * 8 + j], fmaxf(acc[j], 0.f));
}

__global__ void node_small(const unsigned short* __restrict__ x, const float* __restrict__ Agg,
                           const float* __restrict__ Wn, const float* __restrict__ bn,
                           float* __restrict__ out)
{
    __shared__ float sW[136 * 8];
    for (int idx = threadIdx.x; idx < 136 * 8; idx += 256) sW[idx] = Wn[idx];
    __syncthreads();
    int n = blockIdx.x * 256 + threadIdx.x;
    if (n >= NN) return;
    float acc[8];
    #pragma unroll
    for (int j = 0; j < 8; ++j) acc[j] = bn[j];
    const unsigned short* xr = x + (long long)n * HD;
    for (int k8 = 0; k8 < HD / 8; ++k8) {
        u16x8 v = *(const u16x8*)(xr + k8 * 8);
        #pragma unroll
        for (int c = 0; c < 8; ++c) {
            float f = b2f(v[c]);
            #pragma unroll
            for (int j = 0; j < 8; ++j)
                acc[j] = fmaf(f, sW[(k8 * 8 + c) * 8 + j], acc[j]);
        }
    }
    const float* ar = Agg + (long long)n * 8;
    #pragma unroll
    for (int c = 0; c < 8; ++c) {
        float v = ar[c];
        #pragma unroll
        for (int j = 0; j < 8; ++j)
            acc[j] = fmaf(v, sW[(HD + c) * 8 + j], acc[j]);
    }
    #pragma unroll
    for (int j = 0; j < 8; ++j)
        out[(long long)n * 8 + j] = fmaxf(acc[j], 0.f);
}

extern "C" void kernel_launch(void* const* d_in, const int* in_sizes, int n_in,
                              void* d_out, int out_size, void* d_ws, size_t ws_size,
                              hipStream_t stream) {
    const float* x    = (const float*)d_in[0];
    const int*   ei   = (const int*)d_in[1];
    const float* ea   = (const float*)d_in[2];
    const float* We1  = (const float*)d_in[3];
    const float* be1  = (const float*)d_in[4];
    const float* Wn1  = (const float*)d_in[5];
    const float* bn1  = (const float*)d_in[6];
    const float* WeM  = (const float*)d_in[7];
    const float* beM  = (const float*)d_in[8];
    const float* WnM  = (const float*)d_in[9];
    const float* bnM  = (const float*)d_in[10];
    const float* WeC  = (const float*)d_in[11];
    const float* beC  = (const float*)d_in[12];
    const float* WnC  = (const float*)d_in[13];
    const float* bnC  = (const float*)d_in[14];
    const float* WeL  = (const float*)d_in[15];
    const float* beL  = (const float*)d_in[16];
    const float* WnL  = (const float*)d_in[17];
    const float* bnL  = (const float*)d_in[18];

    char* w = (char*)d_ws;
    auto alloc = [&](size_t bytes) -> char* {
        char* p = w; w += (bytes + 255) & ~(size_t)255; return p;
    };
    float*          Agg  = (float*)         alloc((size_t)NN * HD * 4);
    unsigned short* XS   = (unsigned short*)alloc((size_t)NN * 7 * HD * 2);
    unsigned short* HC   = (unsigned short*)alloc((size_t)NN * HD * 2);
    unsigned short* XB   = (unsigned short*)alloc((size_t)NN * 8 * 2);
    unsigned short* WTeM = (unsigned short*)alloc((size_t)6 * HD * 128 * 2);
    unsigned short* WTeC = (unsigned short*)alloc((size_t)HD * 896 * 2);
    unsigned short* WTnM = (unsigned short*)alloc((size_t)6 * HD * 256 * 2);
    unsigned short* WTnC = (unsigned short*)alloc((size_t)HD * 1024 * 2);
    float* out = (float*)d_out;

    const int* src = ei;
    const int* dst = ei + NE;

    // --- weight conversions (bf16, transposed)
    cvt_bf16<<<(NN * 8 + 255) / 256, 256, 0, stream>>>(x, XB, NN * 8);
    for (int i = 0; i < 6; ++i) {
        cvt_transpose<<<(128 * HD + 255) / 256, 256, 0, stream>>>(WeM + (size_t)i * 132 * HD, WTeM + (size_t)i * HD * 128, 128);
        cvt_transpose<<<(256 * HD + 255) / 256, 256, 0, stream>>>(WnM + (size_t)i * 256 * HD, WTnM + (size_t)i * HD * 256, 256);
    }
    cvt_transpose<<<(896 * HD + 255) / 256, 256, 0, stream>>>(WeC, WTeC, 896);
    cvt_transpose<<<(1024 * HD + 255) / 256, 256, 0, stream>>>(WnC, WTnC, 1024);

    const int egrid = NE / 128;            // 2500
    const int ngrid = (NN + 127) / 128;    // 157

    // --- layer 1 (fp32 path, K small)
    hipMemsetAsync(Agg, 0, (size_t)NN * HD * 4, stream);
    gemm_layer<true, false><<<egrid, 256, 0, stream>>>(XB, 8, 8, ea, 4, src, dst,
                                                       We1, be1, Agg, nullptr, HD, NE, 12);
    gemm_layer<false, true><<<ngrid, 256, 0, stream>>>(XB, 8, 8, Agg, HD, nullptr, nullptr,
                                                       Wn1, bn1, nullptr, XS, 7 * HD, NN, 136);

    // --- layers 2..7 (MFMA)
    for (int i = 0; i < 6; ++i) {
        hipMemsetAsync(Agg, 0, (size_t)NN * HD * 4, stream);
        mfma_layer<true><<<egrid, 256, 0, stream>>>(XS, 7 * HD, i * HD, HD,
                                                    nullptr, 0, src, dst,
                                                    WTeM + (size_t)i * HD * 128, beM + i * HD,
                                                    WeM + (size_t)i * 132 * HD + (size_t)128 * HD, ea,
                                                    Agg, nullptr, 0, 0, NE, 128);
        mfma_layer<false><<<ngrid, 256, 0, stream>>>(XS, 7 * HD, i * HD, HD,
                                                     Agg, HD, nullptr, nullptr,
                                                     WTnM + (size_t)i * HD * 256, bnM + i * HD,
                                                     nullptr, nullptr,
                                                     nullptr, XS, 7 * HD, (i + 1) * HD, NN, 256);
    }

    // --- concat layer (MFMA, K=896 / 1024)
    hipMemsetAsync(Agg, 0, (size_t)NN * HD * 4, stream);
    mfma_layer<true><<<egrid, 256, 0, stream>>>(XS, 7 * HD, 0, 7 * HD,
                                                nullptr, 0, src, dst,
                                                WTeC, beC, WeC + (size_t)896 * HD, ea,
                                                Agg, nullptr, 0, 0, NE, 896);
    mfma_layer<false><<<ngrid, 256, 0, stream>>>(XS, 7 * HD, 0, 7 * HD,
                                                 Agg, HD, nullptr, nullptr,
                                                 WTnC, bnC, nullptr, nullptr,
                                                 nullptr, HC, HD, 0, NN, 1024);

    // --- last layer (Hout=8)
    hipMemsetAsync(Agg, 0, (size_t)NN * 8 * 4, stream);
    edge_small<<<NE / 256, 256, 0, stream>>>(HC, ei, ea, WeL, beL, Agg);
    node_small<<<(NN + 255) / 256, 256, 0, stream>>>(HC, Agg, WnL, bnL, out);
}

// Round 4
// 999.118 us; speedup vs baseline: 26.3092x; 1.5720x over previous
//
#include <hip/hip_runtime.h>

#define NN 20000
#define NE 320000
#define HD 128

typedef short     s16x8 __attribute__((ext_vector_type(8)));
typedef unsigned short u16x8 __attribute__((ext_vector_type(8)));
typedef unsigned short u16x4 __attribute__((ext_vector_type(4)));
typedef float     f32x4 __attribute__((ext_vector_type(4)));

__device__ __forceinline__ float b2f(unsigned short u) {
    union { unsigned int i; float f; } c; c.i = ((unsigned int)u) << 16; return c.f;
}
__device__ __forceinline__ unsigned short f2b(float f) {
    union { float f; unsigned int i; } c; c.f = f;
    unsigned int x = c.i + 0x7FFFu + ((c.i >> 16) & 1u);
    return (unsigned short)(x >> 16);
}

__global__ void cvt_bf16(const float* __restrict__ in, unsigned short* __restrict__ out, int n) {
    int i = blockIdx.x * 256 + threadIdx.x;
    if (i < n) out[i] = f2b(in[i]);
}

// WT[n*K + k] = bf16(W[k*128 + n])
__global__ void cvt_transpose(const float* __restrict__ W, unsigned short* __restrict__ WT, int K) {
    int tid = blockIdx.x * 256 + threadIdx.x;
    if (tid >= K * HD) return;
    int n = tid & (HD - 1), k = tid >> 7;
    WT[(size_t)n * K + k] = f2b(W[(size_t)k * HD + n]);
}

// ---------------- CSR build (sort edges by dst) ----------------
__global__ void hist_kernel(const int* __restrict__ ei, int* __restrict__ cnt) {
    int e = blockIdx.x * 256 + threadIdx.x;
    if (e < NE) atomicAdd(&cnt[ei[NE + e]], 1);
}

__global__ void scan_kernel(const int* __restrict__ cnt, int* __restrict__ rowptr) {
    __shared__ int s[256];
    __shared__ int carry;
    int t = threadIdx.x;
    if (t == 0) carry = 0;
    __syncthreads();
    for (int base = 0; base < NN; base += 256) {
        int v = (base + t < NN) ? cnt[base + t] : 0;
        s[t] = v; __syncthreads();
        #pragma unroll
        for (int off = 1; off < 256; off <<= 1) {
            int add = (t >= off) ? s[t - off] : 0;
            __syncthreads();
            s[t] += add;
            __syncthreads();
        }
        int incl = s[t];
        if (base + t < NN) rowptr[base + t] = carry + incl - v;
        __syncthreads();
        if (t == 255) carry += incl;
        __syncthreads();
    }
    if (t == 0) rowptr[NN] = NE;
}

// pos assignment + pre-gather of src and edge attrs into sorted order
__global__ void scatter_kernel(const int* __restrict__ ei, const float* __restrict__ ea,
                               const int* __restrict__ rowptr, int* __restrict__ cursor,
                               int* __restrict__ srcS, float* __restrict__ eaS,
                               unsigned short* __restrict__ eaSB) {
    int e = blockIdx.x * 256 + threadIdx.x;
    if (e >= NE) return;
    int d = ei[NE + e];
    int pos = rowptr[d] + atomicAdd(&cursor[d], 1);
    srcS[pos] = ei[e];
    float4 v = *(const float4*)(ea + (long long)e * 4);
    *(float4*)(eaS + (long long)pos * 4) = v;
    u16x4 b; b[0] = f2b(v.x); b[1] = f2b(v.y); b[2] = f2b(v.z); b[3] = f2b(v.w);
    *(u16x4*)(eaSB + (long long)pos * 4) = b;
}

// segment-sum: Agg[n][:] = sum of msg rows rowptr[n]..rowptr[n+1]
__global__ void agg_kernel(const unsigned short* __restrict__ msg,
                           const int* __restrict__ rowptr,
                           unsigned short* __restrict__ AggB) {
    int t = threadIdx.x;
    int n = blockIdx.x * 16 + (t >> 4);
    int cg = t & 15;
    if (n >= NN) return;
    int s = rowptr[n], e = rowptr[n + 1];
    float a[8];
    #pragma unroll
    for (int j = 0; j < 8; ++j) a[j] = 0.f;
    for (int p = s; p < e; ++p) {
        u16x8 v = *(const u16x8*)(msg + (long long)p * HD + cg * 8);
        #pragma unroll
        for (int j = 0; j < 8; ++j) a[j] += b2f(v[j]);
    }
    u16x8 o;
    #pragma unroll
    for (int j = 0; j < 8; ++j) o[j] = f2b(a[j]);
    *(u16x8*)(AggB + (long long)n * HD + cg * 8) = o;
}

// ---------------- MFMA layer, N=128. A row = [seg1 (D1 bf16, opt gather) | seg2 bf16].
// EDGE: + ea@Wea epilogue, stores msg rows (sorted). else: stores OutB[row*ostride+ooff].
// LDS slot-major [chunk 0..3][row 0..127][8 bf16] -> conflict-free b128.
template<bool EDGE>
__global__ __launch_bounds__(256)
void mfma_layer(const unsigned short* __restrict__ seg1, long long s1, int xoff, int D1,
                const unsigned short* __restrict__ seg2, long long s2,
                const int* __restrict__ srcidx,
                const unsigned short* __restrict__ WT,   // [128][K] bf16
                const float* __restrict__ bias,
                const float* __restrict__ Wea,           // [4][128] fp32 (EDGE)
                const float* __restrict__ eaS,           // [E][4] fp32 sorted (EDGE)
                unsigned short* __restrict__ OutB, long long ostride, int ooff,
                int M, int K)
{
    __shared__ unsigned short As[4 * 128 * 8];
    __shared__ unsigned short Bs[4 * 128 * 8];
    __shared__ float eas[128 * 4];

    const int t    = threadIdx.x;
    const int lane = t & 63;
    const int wid  = t >> 6;
    const int wm   = wid >> 1, wn = wid & 1;
    const int ln   = lane & 15, kb = lane >> 4;
    const int bRow = blockIdx.x * 128;

    const int srow = t >> 1, half = t & 1;
    int gr  = bRow + srow;
    int grc = gr < M ? gr : M - 1;
    long long r1 = srcidx ? (long long)srcidx[grc] : (long long)grc;
    const unsigned short* p1 = seg1 + r1 * s1 + xoff;
    const unsigned short* p2 = seg2 ? seg2 + (long long)grc * s2 : nullptr;
    const unsigned short* pb = WT + (long long)srow * K;
    const int c0 = half * 2, c1 = half * 2 + 1;

    if (EDGE && t < 128) {
        int er = bRow + t;
        if (er < M) *(float4*)&eas[t * 4] = *(const float4*)(eaS + (long long)er * 4);
    }

    f32x4 acc[4][4];
    #pragma unroll
    for (int m = 0; m < 4; ++m)
        #pragma unroll
        for (int n = 0; n < 4; ++n) acc[m][n] = f32x4{0.f, 0.f, 0.f, 0.f};

    const int nkt = K >> 5;
    for (int kt = 0; kt < nkt; ++kt) {
        int k0 = (kt << 5) + half * 16;
        const u16x8* sp = (k0 + 16 <= D1) ? (const u16x8*)(p1 + k0)
                                          : (const u16x8*)(p2 + (k0 - D1));
        u16x8 a0 = sp[0], a1 = sp[1];
        *(u16x8*)&As[(c0 * 128 + srow) * 8] = a0;
        *(u16x8*)&As[(c1 * 128 + srow) * 8] = a1;
        const u16x8* bp = (const u16x8*)(pb + (kt << 5) + half * 16);
        u16x8 b0 = bp[0], b1 = bp[1];
        *(u16x8*)&Bs[(c0 * 128 + srow) * 8] = b0;
        *(u16x8*)&Bs[(c1 * 128 + srow) * 8] = b1;
        __syncthreads();

        s16x8 af[4], bfr[4];
        #pragma unroll
        for (int m = 0; m < 4; ++m)
            af[m] = *(const s16x8*)&As[(kb * 128 + wm * 64 + m * 16 + ln) * 8];
        #pragma unroll
        for (int n = 0; n < 4; ++n)
            bfr[n] = *(const s16x8*)&Bs[(kb * 128 + wn * 64 + n * 16 + ln) * 8];
        #pragma unroll
        for (int m = 0; m < 4; ++m)
            #pragma unroll
            for (int n = 0; n < 4; ++n)
                acc[m][n] = __builtin_amdgcn_mfma_f32_16x16x32_bf16(af[m], bfr[n], acc[m][n], 0, 0, 0);
        __syncthreads();
    }

    float bv[4];
    #pragma unroll
    for (int n = 0; n < 4; ++n) bv[n] = bias[wn * 64 + n * 16 + ln];

    if (EDGE) {
        float we[4][4];
        #pragma unroll
        for (int c = 0; c < 4; ++c)
            #pragma unroll
            for (int n = 0; n < 4; ++n) we[c][n] = Wea[c * HD + wn * 64 + n * 16 + ln];
        #pragma unroll
        for (int m = 0; m < 4; ++m) {
            #pragma unroll
            for (int r = 0; r < 4; ++r) {
                int lrow = wm * 64 + m * 16 + kb * 4 + r;
                int grow = bRow + lrow;
                if (grow < M) {
                    float4 e4 = *(const float4*)&eas[lrow * 4];
                    unsigned short* op = OutB + (long long)grow * HD;
                    #pragma unroll
                    for (int n = 0; n < 4; ++n) {
                        float v = acc[m][n][r] + bv[n]
                                + e4.x * we[0][n] + e4.y * we[1][n]
                                + e4.z * we[2][n] + e4.w * we[3][n];
                        op[wn * 64 + n * 16 + ln] = f2b(fmaxf(v, 0.f));
                    }
                }
            }
        }
    } else {
        #pragma unroll
        for (int m = 0; m < 4; ++m) {
            #pragma unroll
            for (int r = 0; r < 4; ++r) {
                int grow = bRow + wm * 64 + m * 16 + kb * 4 + r;
                if (grow < M) {
                    unsigned short* op = OutB + (long long)grow * ostride + ooff;
                    #pragma unroll
                    for (int n = 0; n < 4; ++n)
                        op[wn * 64 + n * 16 + ln] = f2b(fmaxf(acc[m][n][r] + bv[n], 0.f));
                }
            }
        }
    }
}

// ---------------- fp32 GEMM for layer 1 (small/odd K). Both segs bf16. Stores bf16.
__global__ __launch_bounds__(256, 4)
void gemm_layer(const unsigned short* __restrict__ base1, int s1, int D,
                const unsigned short* __restrict__ base2, int s2,
                const int* __restrict__ srcidx,
                const float* __restrict__ W, const float* __restrict__ bias,
                unsigned short* __restrict__ OutB, long long ostride, int ooff,
                int M, int Ktot)
{
    __shared__ float As[128][33];
    __shared__ float Bs[32 * 128];

    const int t  = threadIdx.x;
    const int tx = t & 15;
    const int ty = t >> 4;
    const int srow  = t >> 1;
    const int kbase = (t & 1) * 16;
    int gr  = blockIdx.x * 128 + srow;
    int grc = gr < M ? gr : M - 1;
    long long r1 = srcidx ? (long long)srcidx[grc] : (long long)grc;
    const unsigned short* p1 = base1 + r1 * s1;
    const unsigned short* p2 = base2 + (long long)grc * s2;

    float acc[8][8];
    #pragma unroll
    for (int i = 0; i < 8; ++i)
        #pragma unroll
        for (int u = 0; u < 8; ++u) acc[i][u] = 0.f;

    const int ntiles = (Ktot + 31) / 32;
    for (int kt = 0; kt < ntiles; ++kt) {
        #pragma unroll
        for (int i = 0; i < 16; ++i) {
            int gk = kt * 32 + kbase + i;
            float v = 0.f;
            if (gk < D) v = b2f(p1[gk]);
            else if (gk < Ktot) v = b2f(p2[gk - D]);
            As[srow][kbase + i] = v;
        }
        #pragma unroll
        for (int p = 0; p < 4; ++p) {
            int idx = (p * 256 + t) * 4;
            int kk  = idx >> 7;
            int nn  = idx & 127;
            int gk  = kt * 32 + kk;
            float4 v = {0.f, 0.f, 0.f, 0.f};
            if (gk < Ktot) v = *reinterpret_cast<const float4*>(W + (long long)gk * 128 + nn);
            *reinterpret_cast<float4*>(&Bs[kk * 128 + nn]) = v;
        }
        __syncthreads();
        #pragma unroll 8
        for (int kk = 0; kk < 32; ++kk) {
            float a[8], b[8];
            #pragma unroll
            for (int i = 0; i < 8; ++i) a[i] = As[ty * 8 + i][kk];
            #pragma unroll
            for (int u = 0; u < 8; ++u) b[u] = Bs[kk * 128 + tx + 16 * u];
            #pragma unroll
            for (int i = 0; i < 8; ++i)
                #pragma unroll
                for (int u = 0; u < 8; ++u)
                    acc[i][u] = fmaf(a[i], b[u], acc[i][u]);
        }
        __syncthreads();
    }

    float bv[8];
    #pragma unroll
    for (int u = 0; u < 8; ++u) bv[u] = bias[tx + 16 * u];

    #pragma unroll
    for (int i = 0; i < 8; ++i) {
        int orow = blockIdx.x * 128 + ty * 8 + i;
        if (orow < M) {
            unsigned short* op = OutB + (long long)orow * ostride + ooff;
            #pragma unroll
            for (int u = 0; u < 8; ++u)
                op[tx + 16 * u] = f2b(fmaxf(acc[i][u] + bv[u], 0.f));
        }
    }
}

// ---------------- last layer (Hout=8)
__global__ void edge_small(const unsigned short* __restrict__ x,
                           const int* __restrict__ ei, const float* __restrict__ ea,
                           const float* __restrict__ We, const float* __restrict__ be,
                           float* __restrict__ A)
{
    __shared__ float sW[132 * 8];
    for (int idx = threadIdx.x; idx < 132 * 8; idx += 256) sW[idx] = We[idx];
    __syncthreads();
    int e = blockIdx.x * 256 + threadIdx.x;
    if (e >= NE) return;
    int src = ei[e], dst = ei[NE + e];
    float acc[8];
    #pragma unroll
    for (int j = 0; j < 8; ++j) acc[j] = be[j];
    const unsigned short* xr = x + (long long)src * HD;
    for (int k8 = 0; k8 < HD / 8; ++k8) {
        u16x8 v = *(const u16x8*)(xr + k8 * 8);
        #pragma unroll
        for (int c = 0; c < 8; ++c) {
            float f = b2f(v[c]);
            #pragma unroll
            for (int j = 0; j < 8; ++j)
                acc[j] = fmaf(f, sW[(k8 * 8 + c) * 8 + j], acc[j]);
        }
    }
    #pragma unroll
    for (int c = 0; c < 4; ++c) {
        float v = ea[(long long)e * 4 + c];
        #pragma unroll
        for (int j = 0; j < 8; ++j)
            acc[j] = fmaf(v, sW[(HD + c) * 8 + j], acc[j]);
    }
    #pragma unroll
    for (int j = 0; j < 8; ++j)
        atomicAdd(&A[(long long)dst * 8 + j], fmaxf(acc[j], 0.f));
}

__global__ void node_small(const unsigned short* __restrict__ x, const float* __restrict__ Agg,
                           const float* __restrict__ Wn, const float* __restrict__ bn,
                           float* __restrict__ out)
{
    __shared__ float sW[136 * 8];
    for (int idx = threadIdx.x; idx < 136 * 8; idx += 256) sW[idx] = Wn[idx];
    __syncthreads();
    int n = blockIdx.x * 256 + threadIdx.x;
    if (n >= NN) return;
    float acc[8];
    #pragma unroll
    for (int j = 0; j < 8; ++j) acc[j] = bn[j];
    const unsigned short* xr = x + (long long)n * HD;
    for (int k8 = 0; k8 < HD / 8; ++k8) {
        u16x8 v = *(const u16x8*)(xr + k8 * 8);
        #pragma unroll
        for (int c = 0; c < 8; ++c) {
            float f = b2f(v[c]);
            #pragma unroll
            for (int j = 0; j < 8; ++j)
                acc[j] = fmaf(f, sW[(k8 * 8 + c) * 8 + j], acc[j]);
        }
    }
    const float* ar = Agg + (long long)n * 8;
    #pragma unroll
    for (int c = 0; c < 8; ++c) {
        float v = ar[c];
        #pragma unroll
        for (int j = 0; j < 8; ++j)
            acc[j] = fmaf(v, sW[(HD + c) * 8 + j], acc[j]);
    }
    #pragma unroll
    for (int j = 0; j < 8; ++j)
        out[(long long)n * 8 + j] = fmaxf(acc[j], 0.f);
}

extern "C" void kernel_launch(void* const* d_in, const int* in_sizes, int n_in,
                              void* d_out, int out_size, void* d_ws, size_t ws_size,
                              hipStream_t stream) {
    const float* x    = (const float*)d_in[0];
    const int*   ei   = (const int*)d_in[1];
    const float* ea   = (const float*)d_in[2];
    const float* We1  = (const float*)d_in[3];
    const float* be1  = (const float*)d_in[4];
    const float* Wn1  = (const float*)d_in[5];
    const float* bn1  = (const float*)d_in[6];
    const float* WeM  = (const float*)d_in[7];
    const float* beM  = (const float*)d_in[8];
    const float* WnM  = (const float*)d_in[9];
    const float* bnM  = (const float*)d_in[10];
    const float* WeC  = (const float*)d_in[11];
    const float* beC  = (const float*)d_in[12];
    const float* WnC  = (const float*)d_in[13];
    const float* bnC  = (const float*)d_in[14];
    const float* WeL  = (const float*)d_in[15];
    const float* beL  = (const float*)d_in[16];
    const float* WnL  = (const float*)d_in[17];
    const float* bnL  = (const float*)d_in[18];

    char* w = (char*)d_ws;
    auto alloc = [&](size_t bytes) -> char* {
        char* p = w; w += (bytes + 255) & ~(size_t)255; return p;
    };
    int*            cnt    = (int*)           alloc((size_t)NN * 4);
    int*            cursor = (int*)           alloc((size_t)NN * 4);
    int*            rowptr = (int*)           alloc((size_t)(NN + 1) * 4);
    int*            srcS   = (int*)           alloc((size_t)NE * 4);
    float*          eaS    = (float*)         alloc((size_t)NE * 4 * 4);
    unsigned short* eaSB   = (unsigned short*)alloc((size_t)NE * 4 * 2);
    unsigned short* msg    = (unsigned short*)alloc((size_t)NE * HD * 2);
    unsigned short* XB     = (unsigned short*)alloc((size_t)NN * 8 * 2);
    unsigned short* XS     = (unsigned short*)alloc((size_t)NN * 7 * HD * 2);
    unsigned short* HC     = (unsigned short*)alloc((size_t)NN * HD * 2);
    unsigned short* AggB   = (unsigned short*)alloc((size_t)NN * HD * 2);
    float*          AggS   = (float*)         alloc((size_t)NN * 8 * 4);
    unsigned short* WTeM   = (unsigned short*)alloc((size_t)6 * HD * 128 * 2);
    unsigned short* WTeC   = (unsigned short*)alloc((size_t)HD * 896 * 2);
    unsigned short* WTnM   = (unsigned short*)alloc((size_t)6 * HD * 256 * 2);
    unsigned short* WTnC   = (unsigned short*)alloc((size_t)HD * 1024 * 2);
    float* out = (float*)d_out;

    // --- CSR build
    hipMemsetAsync(cnt, 0, (size_t)NN * 4, stream);
    hipMemsetAsync(cursor, 0, (size_t)NN * 4, stream);
    hist_kernel<<<(NE + 255) / 256, 256, 0, stream>>>(ei, cnt);
    scan_kernel<<<1, 256, 0, stream>>>(cnt, rowptr);
    scatter_kernel<<<(NE + 255) / 256, 256, 0, stream>>>(ei, ea, rowptr, cursor, srcS, eaS, eaSB);

    // --- weight conversions
    cvt_bf16<<<(NN * 8 + 255) / 256, 256, 0, stream>>>(x, XB, NN * 8);
    for (int i = 0; i < 6; ++i) {
        cvt_transpose<<<(128 * HD + 255) / 256, 256, 0, stream>>>(WeM + (size_t)i * 132 * HD, WTeM + (size_t)i * HD * 128, 128);
        cvt_transpose<<<(256 * HD + 255) / 256, 256, 0, stream>>>(WnM + (size_t)i * 256 * HD, WTnM + (size_t)i * HD * 256, 256);
    }
    cvt_transpose<<<(896 * HD + 255) / 256, 256, 0, stream>>>(WeC, WTeC, 896);
    cvt_transpose<<<(1024 * HD + 255) / 256, 256, 0, stream>>>(WnC, WTnC, 1024);

    const int egrid = NE / 128;            // 2500
    const int ngrid = (NN + 127) / 128;    // 157
    const int agrid = (NN + 15) / 16;      // 1250

    // --- layer 1 (fp32 path, K small/odd)
    gemm_layer<<<egrid, 256, 0, stream>>>(XB, 8, 8, eaSB, 4, srcS,
                                          We1, be1, msg, HD, 0, NE, 12);
    agg_kernel<<<agrid, 256, 0, stream>>>(msg, rowptr, AggB);
    gemm_layer<<<ngrid, 256, 0, stream>>>(XB, 8, 8, AggB, HD, nullptr,
                                          Wn1, bn1, XS, 7 * HD, 0, NN, 136);

    // --- layers 2..7 (MFMA)
    for (int i = 0; i < 6; ++i) {
        mfma_layer<true><<<egrid, 256, 0, stream>>>(XS, 7 * HD, i * HD, HD,
                                                    nullptr, 0, srcS,
                                                    WTeM + (size_t)i * HD * 128, beM + i * HD,
                                                    WeM + (size_t)i * 132 * HD + (size_t)128 * HD, eaS,
                                                    msg, HD, 0, NE, 128);
        agg_kernel<<<agrid, 256, 0, stream>>>(msg, rowptr, AggB);
        mfma_layer<false><<<ngrid, 256, 0, stream>>>(XS, 7 * HD, i * HD, HD,
                                                     AggB, HD, nullptr,
                                                     WTnM + (size_t)i * HD * 256, bnM + i * HD,
                                                     nullptr, nullptr,
                                                     XS, 7 * HD, (i + 1) * HD, NN, 256);
    }

    // --- concat layer
    mfma_layer<true><<<egrid, 256, 0, stream>>>(XS, 7 * HD, 0, 7 * HD,
                                                nullptr, 0, srcS,
                                                WTeC, beC, WeC + (size_t)896 * HD, eaS,
                                                msg, HD, 0, NE, 896);
    agg_kernel<<<agrid, 256, 0, stream>>>(msg, rowptr, AggB);
    mfma_layer<false><<<ngrid, 256, 0, stream>>>(XS, 7 * HD, 0, 7 * HD,
                                                 AggB, HD, nullptr,
                                                 WTnC, bnC, nullptr, nullptr,
                                                 HC, HD, 0, NN, 1024);

    // --- last layer (Hout=8)
    hipMemsetAsync(AggS, 0, (size_t)NN * 8 * 4, stream);
    edge_small<<<NE / 256, 256, 0, stream>>>(HC, ei, ea, WeL, beL, AggS);
    node_small<<<(NN + 255) / 256, 256, 0, stream>>>(HC, AggS, WnL, bnL, out);
}